// Round 7
// baseline (145.372 us; speedup 1.0000x reference)
//
#include <hip/hip_runtime.h>
#include <stdint.h>

#define N_NODES 100000
#define N_ELEM4 50000          // nibble-packed element table: 4 bits/node
#define N_EDGES 3200000
#define N_ELEMS 10
#define N_PAIRS (N_ELEMS * N_ELEMS)

#define NB 256                 // node buckets
#define NPB 391                // nodes per bucket: 256*391 = 100096 >= 100000
#define THREADS 1024           // 16 waves/block
#define NBLK 512               // 2 blocks/CU x 256 CU = fully co-resident
#define EPB 6256               // edges per block: 512*6256 = 3,203,072 >= 3.2M
#define NGROUPS (EPB / 4)      // 1564 float4-groups per block
#define NG4 (N_EDGES / 4)      // 800000 float4-groups total
#define PREP_BLOCKS 196        // 196*256 = 50176 >= 50000 node-pair bytes

// Fixed-capacity record slots: records[NB][NBLK][CAP], bucket-major so the
// reduce reads one bucket as a single contiguous 48KB run. CAP=24 vs live
// bucket load lambda~10.5: Poisson tail -> a handful of spills device-wide,
// handled exactly via the overflow list.
#define CAP 24
#define REC_PER_B (NBLK * CAP)        // 12288 uints per bucket
#define OVF_CAP 16384                 // overflow list capacity (huge margin)

// dynamic LDS layout (bytes); reduce-phase bins reuse [0..1564) after the
// grid barrier (all scatter-phase LDS use is complete by then).
#define L_ELEM  0                         // uint4  s_elem4[3125]   50000 B
#define L_TAB   50000                     // float4 s_tab[100]       1600 B (16B aligned)
#define L_CNT   (L_TAB + 1600)            // uint   s_cnt[NB]        1024 B
#define L_REC   (L_CNT + 1024)            // uint   s_rec[NB*CAP]   24576 B
#define LDS_BYTES (L_REC + NB * CAP * 4)  // = 77200 B; x2 = 154400 < 160 KiB/CU

// ---------------------------------------------------------------------------
// Prep: (a) per-node argmax -> 4-bit element idx, packed 2 nodes/byte;
// (b) 100-entry pair table; (c) zero ovf counter + grid-barrier counter
// (poisoned ws cannot self-initialize a barrier, so prep stays separate).
// ---------------------------------------------------------------------------
__global__ __launch_bounds__(256) void prep_kernel(
    const float* __restrict__ node_attrs,
    const int* __restrict__ atomic_numbers,
    const float* __restrict__ covalent_radii,
    uint8_t* __restrict__ node_elem4,
    float4* __restrict__ pair_tab,
    unsigned int* __restrict__ ctrs) {   // [0]=ovf_cnt [1]=bar
  int i = blockIdx.x * 256 + threadIdx.x;   // byte index: nodes 2i, 2i+1

  if (blockIdx.x == 0) {
    if (threadIdx.x < N_PAIRS) {
      int t = threadIdx.x;
      int eu = t / N_ELEMS, ev = t % N_ELEMS;
      float Zuf = (float)atomic_numbers[eu];
      float Zvf = (float)atomic_numbers[ev];
      float a = 0.4543f * 0.529f / (powf(Zuf, 0.3f) + powf(Zvf, 0.3f));
      float rmax = covalent_radii[(int)Zuf] + covalent_radii[(int)Zvf];
      pair_tab[t] = make_float4(1.0f / a, 0.5f * 14.3996f * Zuf * Zvf,
                                rmax, 1.0f / rmax);
    }
    if (threadIdx.x == 0) { ctrs[0] = 0u; ctrs[1] = 0u; }
  }

  if (i < N_ELEM4) {
    unsigned int packed = 0;
#pragma unroll
    for (int h = 0; h < 2; ++h) {
      int node = 2 * i + h;
      const float2* row = (const float2*)(node_attrs + (size_t)node * N_ELEMS);
      float best = -INFINITY;
      int bj = 0;
#pragma unroll
      for (int k = 0; k < 5; ++k) {
        float2 v = row[k];
        if (v.x > best) { best = v.x; bj = 2 * k; }
        if (v.y > best) { best = v.y; bj = 2 * k + 1; }
      }
      packed |= (unsigned int)bj << (h * 4);
    }
    node_elem4[i] = (uint8_t)packed;
  }
}

// ---------------------------------------------------------------------------
// Per-edge math. envelope(p=6): 1 - 28 r^6 + 48 r^7 - 21 r^8, masked x<r_max.
// Returns exactly 0.0f for dead (~57%) edges; live values strictly positive
// -> rec==0 only for empty slots.
// ---------------------------------------------------------------------------
__device__ __forceinline__ float edge_val(float xi, int u, int v,
                                          const uint8_t* s_elem4,
                                          const float4* s_tab) {
  int eu = (s_elem4[u >> 1] >> ((u & 1) * 4)) & 0xF;
  int ev = (s_elem4[v >> 1] >> ((v & 1) * 4)) & 0xF;
  float4 tb = s_tab[eu * N_ELEMS + ev];
  float roa = xi * tb.x;
  float phi = 0.1818f  * __expf(-3.2f    * roa)
            + 0.5099f  * __expf(-0.9423f * roa)
            + 0.2802f  * __expf(-0.4028f * roa)
            + 0.02817f * __expf(-0.2016f * roa);
  float val = tb.y * phi * __builtin_amdgcn_rcpf(xi);
  float r  = xi * tb.w;
  float r2 = r * r;
  float r6 = r2 * r2 * r2;
  float env = 1.0f - 28.0f * r6 + 48.0f * r6 * r - 21.0f * r6 * r2;
  return (xi < tb.z) ? val * env : 0.0f;
}

// ---------------------------------------------------------------------------
// R19: fused scatter+reduce, REGULAR launch (R6 proved cooperative launch is
// dropped under the harness's graph capture: output stayed zero, err ==
// exactly ref-absmax). Manual device-scope barrier instead:
//   - all 512 blocks run the verified R5 scatter (byte-identical)
//   - __syncthreads() drains vmcnt (all dump stores in L2), then each block
//     release-fences + atomicAdd(bar). Blocks 0..255 exit.
//   - blocks 256..511 (dispatched last; and the grid is fully co-resident
//     anyway: launch_bounds(1024,8) caps VGPR<=64, LDS 77.2KB -> 2/CU x 256)
//     spin on bar, acquire-fence (L2 inv, also kills stale poison lines),
//     then run the verified reduce for bucket blockIdx.x-256.
// Removes one dispatch boundary vs R5.
// ---------------------------------------------------------------------------
__global__ __launch_bounds__(THREADS, 8) void scatter_reduce_kernel(
    const float* __restrict__ x,
    const int* __restrict__ edge_index,      // [2, E]
    const uint8_t* __restrict__ node_elem4,
    const float4* __restrict__ pair_tab,
    unsigned int* __restrict__ records,      // [NB][NBLK][CAP]
    unsigned int* __restrict__ ctrs,         // [0]=ovf_cnt [1]=bar
    uint2* __restrict__ ovf,
    float* __restrict__ out) {
  extern __shared__ char smem[];
  uint4*        s_elem4_v = (uint4*)(smem + L_ELEM);
  float4*       s_tab     = (float4*)(smem + L_TAB);
  unsigned int* s_cnt     = (unsigned int*)(smem + L_CNT);
  unsigned int* s_rec     = (unsigned int*)(smem + L_REC);
  const uint8_t* s_elem4  = (const uint8_t*)s_elem4_v;
  unsigned int* ovf_cnt = ctrs;
  unsigned int* bar     = ctrs + 1;

  int tid = threadIdx.x;

  // ---- scatter phase (verified R5 logic) ----
  {
    const uint4* src = (const uint4*)node_elem4;
    for (int j = tid; j < N_ELEM4 / 16; j += THREADS) s_elem4_v[j] = src[j];
  }
  if (tid < N_PAIRS) s_tab[tid] = pair_tab[tid];
  if (tid < NB) s_cnt[tid] = 0u;
  __syncthreads();

#pragma unroll
  for (int k = 0; k < 2; ++k) {
    int gl = k * THREADS + tid;               // local float4-group (< 1564)
    int g  = blockIdx.x * NGROUPS + gl;       // global float4-group
    if (gl >= NGROUPS || g >= NG4) continue;
    int e = g * 4;
    float4 xv = *(const float4*)(x + e);
    int4 uu = *(const int4*)(edge_index + e);
    int4 vv = *(const int4*)(edge_index + N_EDGES + e);
    int ru[4] = {uu.x, uu.y, uu.z, uu.w};
    int rv[4] = {vv.x, vv.y, vv.z, vv.w};
    float xs[4] = {xv.x, xv.y, xv.z, xv.w};
#pragma unroll
    for (int c = 0; c < 4; ++c) {
      float v = edge_val(xs[c], ru[c], rv[c], s_elem4, s_tab);
      if (v != 0.0f) {                 // zero-skip: +0 never changes the sum
        unsigned int b = (unsigned int)rv[c] / NPB;
        unsigned int lid = (unsigned int)rv[c] - b * NPB;
        unsigned int r = atomicAdd(&s_cnt[b], 1u);     // LDS rank (CU-local)
        if (r < CAP) {
          s_rec[b * CAP + r] = (__float_as_uint(v) & ~0x1FFu) | lid;
        } else {                       // rare exact spill
          unsigned int idx = atomicAdd(ovf_cnt, 1u);
          if (idx < OVF_CAP)
            ovf[idx] = make_uint2(__float_as_uint(v), (unsigned int)rv[c]);
        }
      }
    }
  }
  __syncthreads();

  // coalesced dump: every (bucket,slot) written; empty slots = 0.
  for (int j = tid; j < NB * CAP; j += THREADS) {
    int b = j / CAP, slot = j - b * CAP;
    unsigned int c = s_cnt[b]; if (c > CAP) c = CAP;
    unsigned int rec = ((unsigned int)slot < c) ? s_rec[j] : 0u;
    records[(size_t)b * REC_PER_B + (size_t)blockIdx.x * CAP + slot] = rec;
  }

  // ---- manual grid barrier ----
  // __syncthreads drains every wave's vmcnt (stores reach L2); tid0's
  // release fence writes back L2, then device-scope arrive.
  __syncthreads();
  if (tid == 0) {
    __threadfence();
    __hip_atomic_fetch_add(bar, 1u, __ATOMIC_RELEASE,
                           __HIP_MEMORY_SCOPE_AGENT);
  }
  if (blockIdx.x < (NBLK - NB)) return;   // blocks 0..255: done

  if (tid == 0) {
    while (__hip_atomic_load(bar, __ATOMIC_RELAXED,
                             __HIP_MEMORY_SCOPE_AGENT) < NBLK)
      __builtin_amdgcn_s_sleep(2);
    __threadfence();                      // acquire: invalidate L1/L2
  }
  __syncthreads();

  // ---- reduce phase (verified R5 logic; bucket = blockIdx.x - 256) ----
  {
    float* bins = (float*)smem;           // [NPB], LDS reuse is post-barrier
    int b = blockIdx.x - (NBLK - NB);

    if (tid < NPB) bins[tid] = 0.0f;
    __syncthreads();

    const unsigned int* rp = records + (size_t)b * REC_PER_B;
    for (int i = tid; i < REC_PER_B; i += THREADS) {
      unsigned int rec = rp[i];
      if (rec != 0u)
        atomicAdd(&bins[rec & 0x1FFu], __uint_as_float(rec & ~0x1FFu));
    }

    unsigned int on = *ovf_cnt; if (on > OVF_CAP) on = OVF_CAP;
    for (unsigned int j = tid; j < on; j += THREADS) {
      uint2 e2 = ovf[j];
      unsigned int nb = e2.y / NPB;
      if (nb == (unsigned int)b)
        atomicAdd(&bins[e2.y - nb * NPB], __uint_as_float(e2.x));
    }
    __syncthreads();

    int nb0 = b * NPB;
    if (tid < NPB && nb0 + tid < N_NODES) out[nb0 + tid] = bins[tid];
  }
}

// ---------------------------------------------------------------------------
extern "C" void kernel_launch(void* const* d_in, const int* in_sizes, int n_in,
                              void* d_out, int out_size, void* d_ws, size_t ws_size,
                              hipStream_t stream) {
  const float* x              = (const float*)d_in[0];
  const float* node_attrs     = (const float*)d_in[1];
  const int*   edge_index     = (const int*)d_in[2];
  const int*   atomic_numbers = (const int*)d_in[3];
  const float* covalent_radii = (const float*)d_in[4];
  float* out = (float*)d_out;

  // ws layout (aligned sections):
  //   records    uint [NB*NBLK*CAP] = 12,582,912 B @ 0
  //   ctrs       uint[2] (ovf,bar)  =        16 B @ 12,582,912
  //   ovf        uint2[OVF_CAP]     =   131,072 B @ 12,582,928
  //   pair_tab   float4[100]        =     1,600 B @ 12,714,000
  //   node_elem4 uint8[N_ELEM4]     =    50,000 B @ 12,715,600
  char* wsp = (char*)d_ws;
  unsigned int* records    = (unsigned int*)wsp;
  unsigned int* ctrs       = (unsigned int*)(wsp + 12582912);
  uint2*        ovf        = (uint2*)(wsp + 12582928);
  float4*       pair_tab   = (float4*)(wsp + 12714000);
  uint8_t*      node_elem4 = (uint8_t*)(wsp + 12715600);

  prep_kernel<<<PREP_BLOCKS, 256, 0, stream>>>(
      node_attrs, atomic_numbers, covalent_radii, node_elem4, pair_tab, ctrs);

  scatter_reduce_kernel<<<NBLK, THREADS, LDS_BYTES, stream>>>(
      x, edge_index, node_elem4, pair_tab, records, ctrs, ovf, out);
}

// Round 9
// 130.315 us; speedup vs baseline: 1.1155x; 1.1155x over previous
//
#include <hip/hip_runtime.h>
#include <stdint.h>

#define N_NODES 100000
#define N_ELEMW 12500          // nibble-packed element table: 8 nodes/uint32
#define N_EDGES 3200000
#define N_ELEMS 10
#define N_PAIRS (N_ELEMS * N_ELEMS)

#define NB 256                 // node buckets
#define NPB 391                // nodes per bucket: 256*391 = 100096 >= 100000
#define THREADS 1024           // 16 waves/block
#define NBLK 512               // == exact residency: 2/CU x 256 CU
#define NGROUPS 1564           // float4-groups per block: 512*1564 >= 800000
#define NG4 (N_EDGES / 4)      // 800000 float4-groups total

// records[NB][NBLK][CAP], bucket-major; CAP=24 vs live bucket load ~10.5
// (Poisson tail -> spills ~never; exact via overflow list anyway)
#define CAP 24
#define REC_PER_B (NBLK * CAP)        // 12288 uints per bucket
#define OVF_CAP 16384

// dynamic LDS layout (bytes); reduce-phase bins reuse [0..1564) post-barrier
#define L_ELEM  0                         // uint32 s_elem4[12500]  50000 B
#define L_TAB   50000                     // float4 s_tab[100]       1600 B
#define L_CNT   (L_TAB + 1600)            // uint   s_cnt[NB]        1024 B
#define L_REC   (L_CNT + 1024)            // uint   s_rec[NB*CAP]   24576 B
#define LDS_BYTES (L_REC + NB * CAP * 4)  // 77200 B; x2/CU = 154400 < 160 KiB

#define AGENT __HIP_MEMORY_SCOPE_AGENT

// ---------------------------------------------------------------------------
// Per-edge math (verified R5 logic). envelope(p=6): 1 - 28r^6 + 48r^7 - 21r^8,
// masked x<r_max. Dead (~57%) edges return exactly 0.0f; live values are
// strictly positive -> rec==0 only for empty slots.
// ---------------------------------------------------------------------------
__device__ __forceinline__ float edge_val(float xi, int u, int v,
                                          const uint8_t* s_elem4,
                                          const float4* s_tab) {
  int eu = (s_elem4[u >> 1] >> ((u & 1) * 4)) & 0xF;
  int ev = (s_elem4[v >> 1] >> ((v & 1) * 4)) & 0xF;
  float4 tb = s_tab[eu * N_ELEMS + ev];
  float roa = xi * tb.x;
  float phi = 0.1818f  * __expf(-3.2f    * roa)
            + 0.5099f  * __expf(-0.9423f * roa)
            + 0.2802f  * __expf(-0.4028f * roa)
            + 0.02817f * __expf(-0.2016f * roa);
  float val = tb.y * phi * __builtin_amdgcn_rcpf(xi);
  float r  = xi * tb.w;
  float r2 = r * r;
  float r6 = r2 * r2 * r2;
  float env = 1.0f - 28.0f * r6 + 48.0f * r6 * r - 21.0f * r6 * r2;
  return (xi < tb.z) ? val * env : 0.0f;
}

// ---------------------------------------------------------------------------
// R21 = R20 with barrier counters in ws, zeroed by a 12-byte hipMemsetAsync
// node captured into the graph each iteration. R8's tripwire failure was
// SOLELY counter residency: d_out is not re-zeroed across graph replays, so
// replay>=2 saw bar1 = float-bits of out[0] >> 512 and the barriers fell
// through. The coherence scheme (zero cache-maintenance ops) is unchanged:
//   - cross-XCD handoff DATA uses agent-scope relaxed stores/loads (to/from
//     the coherent LLC; R7 measured full-L2 fences at ~45-50us -- banned)
//   - barriers are relaxed agent atomics; __syncthreads() before each
//     arrive drains vmcnt so the write-through stores are at the LLC
//   - grid = 512 = exact residency (77.2KB LDS -> 2/CU; VGPR<=64 via
//     launch_bounds(1024,8)) so spin-barriers cannot starve
// ---------------------------------------------------------------------------
__global__ __launch_bounds__(THREADS, 8) void fused_all(
    const float* __restrict__ x,
    const float* __restrict__ node_attrs,
    const int* __restrict__ edge_index,      // [2, E]
    const int* __restrict__ atomic_numbers,
    const float* __restrict__ covalent_radii,
    unsigned int* __restrict__ node_elem4,   // ws, uint32[12500]
    unsigned int* __restrict__ records,      // ws, [NB][NBLK][CAP]
    unsigned int* __restrict__ ctrs,         // ws, [0]=bar1 [1]=bar2 [2]=ovf
    uint2* __restrict__ ovf,                 // ws
    float* __restrict__ out) {
  extern __shared__ char smem[];
  unsigned int* s_elem4_w = (unsigned int*)(smem + L_ELEM);
  float4*       s_tab     = (float4*)(smem + L_TAB);
  unsigned int* s_cnt     = (unsigned int*)(smem + L_CNT);
  unsigned int* s_rec     = (unsigned int*)(smem + L_REC);
  const uint8_t* s_elem4  = (const uint8_t*)s_elem4_w;

  unsigned int* bar1    = ctrs + 0;
  unsigned int* bar2    = ctrs + 1;
  unsigned int* ovf_cnt = ctrs + 2;

  int tid  = threadIdx.x;
  int gtid = blockIdx.x * THREADS + tid;

  // ---- phase 0a: pair table, computed locally by EVERY block (no handoff)
  if (tid < N_PAIRS) {
    int eu = tid / N_ELEMS, ev = tid % N_ELEMS;
    float Zuf = (float)atomic_numbers[eu];
    float Zvf = (float)atomic_numbers[ev];
    float a = 0.4543f * 0.529f / (powf(Zuf, 0.3f) + powf(Zvf, 0.3f));
    float rmax = covalent_radii[(int)Zuf] + covalent_radii[(int)Zvf];
    s_tab[tid] = make_float4(1.0f / a, 0.5f * 14.3996f * Zuf * Zvf,
                             rmax, 1.0f / rmax);
  }

  // ---- phase 0b: node argmax -> nibble, 8-lane shfl-OR pack, agent store
  // (N_NODES = 100000 is 8-divisible: every 8-lane group is fully active)
  if (gtid < N_NODES) {
    const float2* row = (const float2*)(node_attrs + (size_t)gtid * N_ELEMS);
    float best = -INFINITY;
    int bj = 0;
#pragma unroll
    for (int k = 0; k < 5; ++k) {
      float2 v = row[k];
      if (v.x > best) { best = v.x; bj = 2 * k; }
      if (v.y > best) { best = v.y; bj = 2 * k + 1; }
    }
    unsigned int nib = (unsigned int)bj << ((gtid & 7) * 4);
    nib |= (unsigned int)__shfl_xor((int)nib, 1, 64);
    nib |= (unsigned int)__shfl_xor((int)nib, 2, 64);
    nib |= (unsigned int)__shfl_xor((int)nib, 4, 64);
    if ((gtid & 7) == 0)
      __hip_atomic_store(&node_elem4[gtid >> 3], nib, __ATOMIC_RELAXED, AGENT);
  }

  // ---- barrier 1 (arrive after vmcnt drained by syncthreads; spin >=) ----
  __syncthreads();
  if (tid == 0) {
    __hip_atomic_fetch_add(bar1, 1u, __ATOMIC_RELAXED, AGENT);
    while (__hip_atomic_load(bar1, __ATOMIC_RELAXED, AGENT) < (unsigned)NBLK)
      __builtin_amdgcn_s_sleep(2);
  }
  __syncthreads();

  // ---- stage elem table into LDS via agent loads (fresh from LLC) ----
  for (int j = tid; j < N_ELEMW; j += THREADS)
    s_elem4_w[j] = __hip_atomic_load(&node_elem4[j], __ATOMIC_RELAXED, AGENT);
  if (tid < NB) s_cnt[tid] = 0u;
  __syncthreads();

  // ---- scatter (verified R5 logic) ----
#pragma unroll
  for (int k = 0; k < 2; ++k) {
    int gl = k * THREADS + tid;               // local float4-group (< 1564)
    int g  = blockIdx.x * NGROUPS + gl;       // global float4-group
    if (gl >= NGROUPS || g >= NG4) continue;
    int e = g * 4;
    float4 xv = *(const float4*)(x + e);
    int4 uu = *(const int4*)(edge_index + e);
    int4 vv = *(const int4*)(edge_index + N_EDGES + e);
    int ru[4] = {uu.x, uu.y, uu.z, uu.w};
    int rv[4] = {vv.x, vv.y, vv.z, vv.w};
    float xs[4] = {xv.x, xv.y, xv.z, xv.w};
#pragma unroll
    for (int c = 0; c < 4; ++c) {
      float v = edge_val(xs[c], ru[c], rv[c], s_elem4, s_tab);
      if (v != 0.0f) {                 // zero-skip: +0 never changes the sum
        unsigned int b = (unsigned int)rv[c] / NPB;
        unsigned int lid = (unsigned int)rv[c] - b * NPB;
        unsigned int r = atomicAdd(&s_cnt[b], 1u);     // LDS rank (CU-local)
        if (r < CAP) {
          s_rec[b * CAP + r] = (__float_as_uint(v) & ~0x1FFu) | lid;
        } else {                       // ~never (Poisson tail): exact spill
          unsigned int idx =
              __hip_atomic_fetch_add(ovf_cnt, 1u, __ATOMIC_RELAXED, AGENT);
          if (idx < OVF_CAP) {
            __hip_atomic_store(&ovf[idx].x, __float_as_uint(v),
                               __ATOMIC_RELAXED, AGENT);
            __hip_atomic_store(&ovf[idx].y, (unsigned int)rv[c],
                               __ATOMIC_RELAXED, AGENT);
          }
        }
      }
    }
  }
  __syncthreads();

  // ---- dump: coalesced agent stores (write-through); empty slots = 0 ----
  for (int j = tid; j < NB * CAP; j += THREADS) {
    int b = j / CAP, slot = j - b * CAP;
    unsigned int c = s_cnt[b]; if (c > CAP) c = CAP;
    unsigned int rec = ((unsigned int)slot < c) ? s_rec[j] : 0u;
    __hip_atomic_store(
        &records[(size_t)b * REC_PER_B + (size_t)blockIdx.x * CAP + slot],
        rec, __ATOMIC_RELAXED, AGENT);
  }

  // ---- barrier 2 ----
  __syncthreads();                      // drains vmcnt: dump is at the LLC
  if (tid == 0)
    __hip_atomic_fetch_add(bar2, 1u, __ATOMIC_RELAXED, AGENT);
  if (blockIdx.x < (NBLK - NB)) return; // blocks 0..255: done

  if (tid == 0) {
    while (__hip_atomic_load(bar2, __ATOMIC_RELAXED, AGENT) < (unsigned)NBLK)
      __builtin_amdgcn_s_sleep(2);
  }
  __syncthreads();

  // ---- reduce (verified R5 logic; bucket = blockIdx.x - 256) ----
  {
    float* bins = (float*)smem;         // LDS reuse, post-barrier
    int b = blockIdx.x - (NBLK - NB);

    unsigned int on =
        __hip_atomic_load(ovf_cnt, __ATOMIC_RELAXED, AGENT);
    if (on > OVF_CAP) on = OVF_CAP;

    if (tid < NPB) bins[tid] = 0.0f;
    __syncthreads();

    unsigned int* rp = records + (size_t)b * REC_PER_B;
    for (int i = tid; i < REC_PER_B; i += THREADS) {
      unsigned int rec = __hip_atomic_load(&rp[i], __ATOMIC_RELAXED, AGENT);
      if (rec != 0u)
        atomicAdd(&bins[rec & 0x1FFu], __uint_as_float(rec & ~0x1FFu));
    }

    for (unsigned int j = tid; j < on; j += THREADS) {
      unsigned int ox = __hip_atomic_load(&ovf[j].x, __ATOMIC_RELAXED, AGENT);
      unsigned int oy = __hip_atomic_load(&ovf[j].y, __ATOMIC_RELAXED, AGENT);
      unsigned int nb = oy / NPB;
      if (nb == (unsigned int)b)
        atomicAdd(&bins[oy - nb * NPB], __uint_as_float(ox));
    }
    __syncthreads();

    int nb0 = b * NPB;
    if (tid < NPB && nb0 + tid < N_NODES) out[nb0 + tid] = bins[tid];
  }
}

// ---------------------------------------------------------------------------
extern "C" void kernel_launch(void* const* d_in, const int* in_sizes, int n_in,
                              void* d_out, int out_size, void* d_ws, size_t ws_size,
                              hipStream_t stream) {
  const float* x              = (const float*)d_in[0];
  const float* node_attrs     = (const float*)d_in[1];
  const int*   edge_index     = (const int*)d_in[2];
  const int*   atomic_numbers = (const int*)d_in[3];
  const float* covalent_radii = (const float*)d_in[4];
  float* out = (float*)d_out;

  // ws layout (aligned sections):
  //   records    uint [NB*NBLK*CAP] = 12,582,912 B @ 0
  //   ctrs       uint[3]            =        16 B @ 12,582,912
  //   ovf        uint2[OVF_CAP]     =   131,072 B @ 12,582,928
  //   node_elem4 uint32[12500]      =    50,000 B @ 12,714,000
  char* wsp = (char*)d_ws;
  unsigned int* records    = (unsigned int*)wsp;
  unsigned int* ctrs       = (unsigned int*)(wsp + 12582912);
  uint2*        ovf        = (uint2*)(wsp + 12582928);
  unsigned int* node_elem4 = (unsigned int*)(wsp + 12714000);

  // 12-byte stream-ordered zero of {bar1, bar2, ovf_cnt}: graph-capturable
  // memset node (the harness's own reset uses memset nodes), replaces the
  // d_out-resident counters that broke R8 on graph replay.
  hipMemsetAsync(ctrs, 0, 12, stream);

  fused_all<<<NBLK, THREADS, LDS_BYTES, stream>>>(
      x, node_attrs, edge_index, atomic_numbers, covalent_radii,
      node_elem4, records, ctrs, ovf, out);
}

// Round 10
// 105.063 us; speedup vs baseline: 1.3837x; 1.2404x over previous
//
#include <hip/hip_runtime.h>
#include <stdint.h>

#define N_NODES 100000
#define N_ELEM4 50000          // nibble-packed element table: 4 bits/node
#define N_EDGES 3200000
#define N_ELEMS 10
#define N_PAIRS (N_ELEMS * N_ELEMS)

#define NB 256                 // node buckets
#define NPB 391                // nodes per bucket: 256*391 = 100096 >= 100000
#define SCAT_THREADS 1024      // 16 waves/block; 77.2 KB LDS -> 2 blocks/CU
#define NBLK 512               // scatter blocks
#define EPB 6256               // edges per block: 512*6256 = 3,203,072 >= 3.2M
#define NGROUPS (EPB / 4)      // 1564 float4-groups per block
#define NG4 (N_EDGES / 4)      // 800000 float4-groups total
#define PREP_BLOCKS 196        // 196*256 = 50176 >= 50000 node-pair bytes

// records[NB][NBLK][CAP], bucket-major; CAP=24 vs live bucket load ~10.5
// (Poisson tail P(>24|lam=10.5) ~ 1e-4 -> ~15 spills device-wide, exact via
// the overflow list)
#define CAP 24
#define REC_PER_B (NBLK * CAP)        // 12288 uints per bucket
#define OVF_CAP 16384

// dynamic LDS layout for scatter (bytes)
#define L_ELEM  0                         // uint4  s_elem4[3125]   50000 B
#define L_TAB   50000                     // float4 s_tab[100]       1600 B (16B aligned)
#define L_CNT   (L_TAB + 1600)            // uint   s_cnt[NB]        1024 B
#define L_REC   (L_CNT + 1024)            // uint   s_rec[NB*CAP]   24576 B
#define LDS_BYTES (L_REC + NB * CAP * 4)  // = 77200 B; x2 = 154400 < 160 KiB/CU

// ---------------------------------------------------------------------------
// Prep (verbatim R5): per-node argmax nibble table, pair table, zero ovf.
// ---------------------------------------------------------------------------
__global__ __launch_bounds__(256) void prep_kernel(
    const float* __restrict__ node_attrs,
    const int* __restrict__ atomic_numbers,
    const float* __restrict__ covalent_radii,
    uint8_t* __restrict__ node_elem4,
    float4* __restrict__ pair_tab,
    unsigned int* __restrict__ ovf_cnt) {
  int i = blockIdx.x * 256 + threadIdx.x;   // byte index: nodes 2i, 2i+1

  if (blockIdx.x == 0) {
    if (threadIdx.x < N_PAIRS) {
      int t = threadIdx.x;
      int eu = t / N_ELEMS, ev = t % N_ELEMS;
      float Zuf = (float)atomic_numbers[eu];
      float Zvf = (float)atomic_numbers[ev];
      float a = 0.4543f * 0.529f / (powf(Zuf, 0.3f) + powf(Zvf, 0.3f));
      float rmax = covalent_radii[(int)Zuf] + covalent_radii[(int)Zvf];
      pair_tab[t] = make_float4(1.0f / a, 0.5f * 14.3996f * Zuf * Zvf,
                                rmax, 1.0f / rmax);
    }
    if (threadIdx.x == 0) *ovf_cnt = 0u;
  }

  if (i < N_ELEM4) {
    unsigned int packed = 0;
#pragma unroll
    for (int h = 0; h < 2; ++h) {
      int node = 2 * i + h;
      const float2* row = (const float2*)(node_attrs + (size_t)node * N_ELEMS);
      float best = -INFINITY;
      int bj = 0;
#pragma unroll
      for (int k = 0; k < 5; ++k) {
        float2 v = row[k];
        if (v.x > best) { best = v.x; bj = 2 * k; }
        if (v.y > best) { best = v.y; bj = 2 * k + 1; }
      }
      packed |= (unsigned int)bj << (h * 4);
    }
    node_elem4[i] = (uint8_t)packed;
  }
}

// ---------------------------------------------------------------------------
// Per-edge math (verified). envelope(p=6): 1 - 28r^6 + 48r^7 - 21r^8, masked
// x<r_max. Dead (~57%) edges -> exactly 0.0f; live values strictly positive.
// ---------------------------------------------------------------------------
__device__ __forceinline__ float edge_val(float xi, int u, int v,
                                          const uint8_t* s_elem4,
                                          const float4* s_tab) {
  int eu = (s_elem4[u >> 1] >> ((u & 1) * 4)) & 0xF;
  int ev = (s_elem4[v >> 1] >> ((v & 1) * 4)) & 0xF;
  float4 tb = s_tab[eu * N_ELEMS + ev];
  float roa = xi * tb.x;
  float phi = 0.1818f  * __expf(-3.2f    * roa)
            + 0.5099f  * __expf(-0.9423f * roa)
            + 0.2802f  * __expf(-0.4028f * roa)
            + 0.02817f * __expf(-0.2016f * roa);
  float val = tb.y * phi * __builtin_amdgcn_rcpf(xi);
  float r  = xi * tb.w;
  float r2 = r * r;
  float r6 = r2 * r2 * r2;
  float env = 1.0f - 28.0f * r6 + 48.0f * r6 * r - 21.0f * r6 * r2;
  return (xi < tb.z) ? val * env : 0.0f;
}

// ---------------------------------------------------------------------------
// Phase 2 (R22): R5 scatter with the inner loop SPLIT into
//   pass A (pure): unconditional clamped loads + all LDS gathers + VALU for
//     all 8 edges -> val[8], bl[8] in registers. No side effects, so -O3
//     can issue all 24 LDS reads back-to-back and overlap their latency.
//   pass B (commit): 8 conditional rank-atomics + ranked LDS stores.
// R9 diagnosis: scatter ran ~3x above its VALU floor with every pipe idle
// (VALUBusy 15%, HBM 8.5%, occupancy max) and VGPR_Count=20 -- the compiler
// serialized edges because atomics/branches were interleaved with the
// gathers. launch_bounds(1024,8) caps VGPR at 64 (keeps 2 blocks/CU).
// ---------------------------------------------------------------------------
__global__ __launch_bounds__(SCAT_THREADS, 8) void scatter_kernel(
    const float* __restrict__ x,
    const int* __restrict__ edge_index,      // [2, E]
    const uint8_t* __restrict__ node_elem4,
    const float4* __restrict__ pair_tab,
    unsigned int* __restrict__ records,      // [NB][NBLK][CAP]
    unsigned int* __restrict__ ovf_cnt,
    uint2* __restrict__ ovf) {
  extern __shared__ char smem[];
  uint4*        s_elem4_v = (uint4*)(smem + L_ELEM);
  float4*       s_tab     = (float4*)(smem + L_TAB);
  unsigned int* s_cnt     = (unsigned int*)(smem + L_CNT);
  unsigned int* s_rec     = (unsigned int*)(smem + L_REC);
  const uint8_t* s_elem4  = (const uint8_t*)s_elem4_v;

  int tid = threadIdx.x;

  // stage packed element table (50 KB) + pair table, coalesced uint4 copies
  {
    const uint4* src = (const uint4*)node_elem4;
    for (int j = tid; j < N_ELEM4 / 16; j += SCAT_THREADS) s_elem4_v[j] = src[j];
  }
  if (tid < N_PAIRS) s_tab[tid] = pair_tab[tid];
  if (tid < NB) s_cnt[tid] = 0u;
  __syncthreads();

  float val[8];
  unsigned int bl[8];          // (bucket<<9) | localid  (b<256, lid<391)

  // ---- pass A: pure compute, fully pipelined ----
#pragma unroll
  for (int k = 0; k < 2; ++k) {
    int gl = k * SCAT_THREADS + tid;          // local float4-group (< 2048)
    int g  = blockIdx.x * NGROUPS + gl;       // global float4-group
    bool ok = (gl < NGROUPS) && (g < NG4);
    int gc = ok ? g : (NG4 - 1);              // clamp: loads stay unconditional
    int e = gc * 4;
    float4 xv = *(const float4*)(x + e);
    int4 uu = *(const int4*)(edge_index + e);
    int4 vv = *(const int4*)(edge_index + N_EDGES + e);
    int ru[4] = {uu.x, uu.y, uu.z, uu.w};
    int rv[4] = {vv.x, vv.y, vv.z, vv.w};
    float xs[4] = {xv.x, xv.y, xv.z, xv.w};
#pragma unroll
    for (int c = 0; c < 4; ++c) {
      int j = k * 4 + c;
      float v = edge_val(xs[c], ru[c], rv[c], s_elem4, s_tab);
      val[j] = ok ? v : 0.0f;
      unsigned int b = (unsigned int)rv[c] / NPB;
      unsigned int lid = (unsigned int)rv[c] - b * NPB;
      bl[j] = (b << 9) | lid;
    }
  }

  // ---- pass B: commit (rank + ranked store; zero-skip kills ~57%) ----
#pragma unroll
  for (int j = 0; j < 8; ++j) {
    if (val[j] != 0.0f) {
      unsigned int b = bl[j] >> 9;
      unsigned int r = atomicAdd(&s_cnt[b], 1u);       // LDS rank (CU-local)
      if (r < CAP) {
        s_rec[b * CAP + r] = (__float_as_uint(val[j]) & ~0x1FFu) | (bl[j] & 0x1FFu);
      } else {                                         // ~15 device-wide
        unsigned int idx = atomicAdd(ovf_cnt, 1u);
        if (idx < OVF_CAP) {
          unsigned int node = b * NPB + (bl[j] & 0x1FFu);
          ovf[idx] = make_uint2(__float_as_uint(val[j]), node);
        }
      }
    }
  }
  __syncthreads();

  // coalesced dump: every (bucket,slot) written; empty slots = 0.
  for (int j = tid; j < NB * CAP; j += SCAT_THREADS) {
    int b = j / CAP, slot = j - b * CAP;
    unsigned int c = s_cnt[b]; if (c > CAP) c = CAP;
    unsigned int rec = ((unsigned int)slot < c) ? s_rec[j] : 0u;
    records[(size_t)b * REC_PER_B + (size_t)blockIdx.x * CAP + slot] = rec;
  }
}

// ---------------------------------------------------------------------------
// Phase 3 (verbatim R5): block b reads records[b] as ONE contiguous 48KB
// coalesced run, skips rec==0, LDS float atomics into 391 bins, overflow
// list, coalesced store of every out element.
// ---------------------------------------------------------------------------
__global__ __launch_bounds__(1024) void reduce_kernel(
    const unsigned int* __restrict__ records,
    const unsigned int* __restrict__ ovf_cnt,
    const uint2* __restrict__ ovf,
    float* __restrict__ out) {
  __shared__ float bins[NPB];
  int b = blockIdx.x, tid = threadIdx.x;

  if (tid < NPB) bins[tid] = 0.0f;
  __syncthreads();

  const unsigned int* rp = records + (size_t)b * REC_PER_B;
  for (int i = tid; i < REC_PER_B; i += 1024) {
    unsigned int rec = rp[i];
    if (rec != 0u)
      atomicAdd(&bins[rec & 0x1FFu], __uint_as_float(rec & ~0x1FFu));
  }

  unsigned int on = *ovf_cnt; if (on > OVF_CAP) on = OVF_CAP;
  for (unsigned int j = tid; j < on; j += 1024) {
    uint2 e2 = ovf[j];
    unsigned int nb = e2.y / NPB;
    if (nb == (unsigned int)b)
      atomicAdd(&bins[e2.y - nb * NPB], __uint_as_float(e2.x));
  }
  __syncthreads();

  int nb0 = b * NPB;
  if (tid < NPB && nb0 + tid < N_NODES) out[nb0 + tid] = bins[tid];
}

// ---------------------------------------------------------------------------
extern "C" void kernel_launch(void* const* d_in, const int* in_sizes, int n_in,
                              void* d_out, int out_size, void* d_ws, size_t ws_size,
                              hipStream_t stream) {
  const float* x              = (const float*)d_in[0];
  const float* node_attrs     = (const float*)d_in[1];
  const int*   edge_index     = (const int*)d_in[2];
  const int*   atomic_numbers = (const int*)d_in[3];
  const float* covalent_radii = (const float*)d_in[4];
  float* out = (float*)d_out;

  // ws layout (aligned sections):
  //   records    uint [NB*NBLK*CAP] = 12,582,912 B @ 0
  //   ovf_cnt    uint               =        16 B @ 12,582,912
  //   ovf        uint2[OVF_CAP]     =   131,072 B @ 12,582,928
  //   pair_tab   float4[100]        =     1,600 B @ 12,714,000
  //   node_elem4 uint8[N_ELEM4]     =    50,000 B @ 12,715,600
  char* wsp = (char*)d_ws;
  unsigned int* records    = (unsigned int*)wsp;
  unsigned int* ovf_cnt    = (unsigned int*)(wsp + 12582912);
  uint2*        ovf        = (uint2*)(wsp + 12582928);
  float4*       pair_tab   = (float4*)(wsp + 12714000);
  uint8_t*      node_elem4 = (uint8_t*)(wsp + 12715600);

  prep_kernel<<<PREP_BLOCKS, 256, 0, stream>>>(
      node_attrs, atomic_numbers, covalent_radii, node_elem4, pair_tab,
      ovf_cnt);

  scatter_kernel<<<NBLK, SCAT_THREADS, LDS_BYTES, stream>>>(
      x, edge_index, node_elem4, pair_tab, records, ovf_cnt, ovf);

  reduce_kernel<<<NB, 1024, 0, stream>>>(records, ovf_cnt, ovf, out);
}